// Round 1
// baseline (29716.913 us; speedup 1.0000x reference)
//
#include <hip/hip_runtime.h>
#include <math.h>

// Problem constants
#define NTOK 131072   // 64 * 2048 tokens
#define DDIM 256      // embedding dim
#define KCB  1024     // codebook size

// Output layout (fp32, concatenated in reference return order)
static constexpr size_t O_Q = 1;                          // quantized_st
static constexpr size_t O_P = 1 + (size_t)NTOK * DDIM;    // perplexity scalar
static constexpr size_t O_E = O_P + 1;                    // encodings [NTOK, KCB]
// f-scratch lives inside the (not yet written) encodings region; +2 floats for 16B alignment
static constexpr size_t SCRATCH_F_OFF = O_E + 2;

// ws layout (bytes)
static constexpr size_t WS_IDX = 0;                        // NTOK * int
static constexpr size_t WS_EN  = (size_t)NTOK * 4;         // KCB * float (||e||^2)
static constexpr size_t WS_CNT = WS_EN + (size_t)KCB * 4;  // KCB * uint (histogram)
static constexpr size_t WS_ACC = WS_CNT + (size_t)KCB * 4; // double (loss accumulator)

#define TS 128     // block tile (tokens and k/dims)
#define KC 32      // reduction chunk staged in LDS
#define LDSROW 36  // padded row stride: 4*36 % 32 == 16 -> <=2-way bank aliasing (free)

// ---------------- K1: codebook squared norms ----------------
__global__ __launch_bounds__(64) void k_enorm(const float* __restrict__ emb,
                                              float* __restrict__ enorm) {
    int k = blockIdx.x;
    float4 v = reinterpret_cast<const float4*>(emb)[(size_t)k * 64 + threadIdx.x];
    float s = v.x * v.x + v.y * v.y + v.z * v.z + v.w * v.w;
    for (int off = 32; off >= 1; off >>= 1) s += __shfl_down(s, off, 64);
    if (threadIdx.x == 0) enorm[k] = s;
}

// ---------------- K2: f = x @ W^T + b  (fp32, 128x128 tile, 8x8 micro) ----------------
__global__ __launch_bounds__(256, 2) void k_gemm1(const float* __restrict__ x,
                                                  const float* __restrict__ w,
                                                  const float* __restrict__ b,
                                                  float* __restrict__ f) {
    __shared__ float sA[TS * LDSROW];
    __shared__ float sB[TS * LDSROW];
    const int tid = threadIdx.x;
    const int tx = tid & 15, ty = tid >> 4;
    const int tb = blockIdx.x * TS;   // token base
    const int db = blockIdx.y * TS;   // output-dim base

    float acc[8][8];
#pragma unroll
    for (int j = 0; j < 8; ++j)
#pragma unroll
        for (int c = 0; c < 8; ++c) acc[j][c] = 0.f;

    const float4* x4 = reinterpret_cast<const float4*>(x);
    const float4* w4 = reinterpret_cast<const float4*>(w);

    for (int kc = 0; kc < DDIM / KC; ++kc) {
        __syncthreads();
#pragma unroll
        for (int l0 = 0; l0 < 4; ++l0) {
            int l = l0 * 256 + tid;          // 1024 float4 per tile
            int row = l >> 3, i4 = l & 7;    // 128 rows x 8 float4
            *reinterpret_cast<float4*>(&sA[row * LDSROW + i4 * 4]) =
                x4[(size_t)(tb + row) * 64 + kc * 8 + i4];
            *reinterpret_cast<float4*>(&sB[row * LDSROW + i4 * 4]) =
                w4[(size_t)(db + row) * 64 + kc * 8 + i4];
        }
        __syncthreads();
#pragma unroll
        for (int is = 0; is < 8; ++is) {
            float4 av[8], bv[8];
#pragma unroll
            for (int j = 0; j < 8; ++j)
                av[j] = *reinterpret_cast<const float4*>(&sA[(ty + 16 * j) * LDSROW + is * 4]);
#pragma unroll
            for (int c = 0; c < 8; ++c)
                bv[c] = *reinterpret_cast<const float4*>(&sB[(tx + 16 * c) * LDSROW + is * 4]);
#pragma unroll
            for (int j = 0; j < 8; ++j)
#pragma unroll
                for (int c = 0; c < 8; ++c)
                    acc[j][c] += av[j].x * bv[c].x + av[j].y * bv[c].y +
                                 av[j].z * bv[c].z + av[j].w * bv[c].w;
        }
    }

    float bias[8];
#pragma unroll
    for (int c = 0; c < 8; ++c) bias[c] = b[db + tx + 16 * c];
#pragma unroll
    for (int j = 0; j < 8; ++j) {
        size_t rowo = (size_t)(tb + ty + 16 * j) * DDIM + db;
#pragma unroll
        for (int c = 0; c < 8; ++c)
            f[rowo + tx + 16 * c] = acc[j][c] + bias[c];
    }
}

// ---------------- K3: distances + argmin (fused over all K=1024) ----------------
__global__ __launch_bounds__(256, 2) void k_argmin(const float* __restrict__ f,
                                                   const float* __restrict__ emb,
                                                   const float* __restrict__ enorm,
                                                   int* __restrict__ idx) {
    __shared__ float sA[TS * LDSROW];
    __shared__ float sB[TS * LDSROW];
    const int tid = threadIdx.x;
    const int tx = tid & 15, ty = tid >> 4;
    const int tb = blockIdx.x * TS;
    const float4* f4 = reinterpret_cast<const float4*>(f);
    const float4* e4 = reinterpret_cast<const float4*>(emb);

    float bd[8];
    int   bk[8];
#pragma unroll
    for (int j = 0; j < 8; ++j) { bd[j] = 3.4e38f; bk[j] = 0; }

    for (int kt = 0; kt < KCB / TS; ++kt) {   // 8 code tiles of 128
        float acc[8][8];
#pragma unroll
        for (int j = 0; j < 8; ++j)
#pragma unroll
            for (int c = 0; c < 8; ++c) acc[j][c] = 0.f;

        for (int kc = 0; kc < DDIM / KC; ++kc) {
            __syncthreads();
#pragma unroll
            for (int l0 = 0; l0 < 4; ++l0) {
                int l = l0 * 256 + tid;
                int row = l >> 3, i4 = l & 7;
                *reinterpret_cast<float4*>(&sA[row * LDSROW + i4 * 4]) =
                    f4[(size_t)(tb + row) * 64 + kc * 8 + i4];
                *reinterpret_cast<float4*>(&sB[row * LDSROW + i4 * 4]) =
                    e4[(size_t)(kt * TS + row) * 64 + kc * 8 + i4];
            }
            __syncthreads();
#pragma unroll
            for (int is = 0; is < 8; ++is) {
                float4 av[8], bv[8];
#pragma unroll
                for (int j = 0; j < 8; ++j)
                    av[j] = *reinterpret_cast<const float4*>(&sA[(ty + 16 * j) * LDSROW + is * 4]);
#pragma unroll
                for (int c = 0; c < 8; ++c)
                    bv[c] = *reinterpret_cast<const float4*>(&sB[(tx + 16 * c) * LDSROW + is * 4]);
#pragma unroll
                for (int j = 0; j < 8; ++j)
#pragma unroll
                    for (int c = 0; c < 8; ++c)
                        acc[j][c] += av[j].x * bv[c].x + av[j].y * bv[c].y +
                                     av[j].z * bv[c].z + av[j].w * bv[c].w;
            }
        }
        // epilogue: d = ||e||^2 - 2*dot  (||f||^2 is constant per token -> irrelevant to argmin)
#pragma unroll
        for (int c = 0; c < 8; ++c) {
            int k = kt * TS + tx + 16 * c;
            float en = enorm[k];
#pragma unroll
            for (int j = 0; j < 8; ++j) {
                float d = en - 2.f * acc[j][c];
                if (d < bd[j] || (d == bd[j] && k < bk[j])) { bd[j] = d; bk[j] = k; }
            }
        }
    }

    // cross-lane lexicographic-min over the 16 tx lanes owning each token row
#pragma unroll
    for (int j = 0; j < 8; ++j) {
#pragma unroll
        for (int m = 1; m < 16; m <<= 1) {
            float od = __shfl_xor(bd[j], m, 16);
            int   ok = __shfl_xor(bk[j], m, 16);
            if (od < bd[j] || (od == bd[j] && ok < bk[j])) { bd[j] = od; bk[j] = ok; }
        }
    }
    if (tx == 0) {
#pragma unroll
        for (int j = 0; j < 8; ++j) idx[tb + ty + 16 * j] = bk[j];
    }
}

// ---------------- K4: quantized gather + commitment-loss partial + histogram ----------------
__global__ __launch_bounds__(256) void k_epilogue(const float* __restrict__ x,
                                                  const float* __restrict__ emb,
                                                  const int* __restrict__ idx,
                                                  float* __restrict__ out,
                                                  unsigned* __restrict__ counts,
                                                  double* __restrict__ lossacc) {
    const int tid = threadIdx.x;
    const int tb = blockIdx.x * 64;  // 64 tokens per block
    const float4* x4 = reinterpret_cast<const float4*>(x);
    const float4* e4 = reinterpret_cast<const float4*>(emb);
    float local = 0.f;
#pragma unroll
    for (int it = 0; it < 16; ++it) {
        int l = it * 256 + tid;
        int tok = l >> 6, q = l & 63;   // token-local float4 index
        int t = tb + tok;
        int id = idx[t];                 // wave-uniform (64 lanes share a token)
        if (q == 0) atomicAdd(&counts[id], 1u);
        float4 xv = x4[(size_t)t * 64 + q];
        float4 ev = e4[(size_t)id * 64 + q];
        size_t o = O_Q + (size_t)t * DDIM + (size_t)q * 4;  // O_Q=1 -> scalar stores (16B-misaligned base)
        out[o] = ev.x; out[o + 1] = ev.y; out[o + 2] = ev.z; out[o + 3] = ev.w;
        float dx = ev.x - xv.x, dy = ev.y - xv.y, dz = ev.z - xv.z, dw = ev.w - xv.w;
        local += dx * dx + dy * dy + dz * dz + dw * dw;
    }
    for (int off = 32; off >= 1; off >>= 1) local += __shfl_down(local, off, 64);
    __shared__ float wsum[4];
    if ((tid & 63) == 0) wsum[tid >> 6] = local;
    __syncthreads();
    if (tid == 0)
        atomicAdd(lossacc, (double)(wsum[0] + wsum[1] + wsum[2] + wsum[3]));
}

// ---------------- K5: scatter one-hot 1.0s (after memset of encodings region) ----------------
__global__ __launch_bounds__(256) void k_scatter(const int* __restrict__ idx,
                                                 float* __restrict__ out) {
    int t = blockIdx.x * 256 + threadIdx.x;
    out[O_E + (size_t)t * KCB + idx[t]] = 1.0f;
}

// ---------------- K6: loss + perplexity finalize ----------------
__global__ __launch_bounds__(1024) void k_final(const unsigned* __restrict__ counts,
                                                const double* __restrict__ lossacc,
                                                float* __restrict__ out) {
    int tid = threadIdx.x;
    double p = (double)counts[tid] / (double)NTOK;
    double term = p * log(p + 1e-10);
    for (int off = 32; off >= 1; off >>= 1) term += __shfl_down(term, off, 64);
    __shared__ double sw[16];
    if ((tid & 63) == 0) sw[tid >> 6] = term;
    __syncthreads();
    if (tid == 0) {
        double s = 0.0;
        for (int i = 0; i < 16; ++i) s += sw[i];
        out[O_P] = (float)exp(-s);
        out[0]   = (float)(0.25 * lossacc[0] / ((double)NTOK * (double)DDIM));
    }
}

extern "C" void kernel_launch(void* const* d_in, const int* in_sizes, int n_in,
                              void* d_out, int out_size, void* d_ws, size_t ws_size,
                              hipStream_t stream) {
    const float* x   = (const float*)d_in[0];  // [64,2048,256]
    const float* w   = (const float*)d_in[1];  // [256,256]
    const float* b   = (const float*)d_in[2];  // [256]
    const float* emb = (const float*)d_in[3];  // [1024,256]
    float* out = (float*)d_out;

    int*      idx    = (int*)((char*)d_ws + WS_IDX);
    float*    enorm  = (float*)((char*)d_ws + WS_EN);
    unsigned* counts = (unsigned*)((char*)d_ws + WS_CNT);
    double*   acc    = (double*)((char*)d_ws + WS_ACC);
    float* scratchF  = out + SCRATCH_F_OFF;    // f staged inside encodings region (written later)

    // zero histogram + loss accumulator (ws is poisoned 0xAA each launch)
    hipMemsetAsync((char*)d_ws + WS_CNT, 0, (size_t)KCB * 4 + 8, stream);

    k_enorm  <<<KCB,                          64,  0, stream>>>(emb, enorm);
    k_gemm1  <<<dim3(NTOK / TS, DDIM / TS),   256, 0, stream>>>(x, w, b, scratchF);
    k_argmin <<<NTOK / TS,                    256, 0, stream>>>(scratchF, emb, enorm, idx);
    k_epilogue<<<NTOK / 64,                   256, 0, stream>>>(x, emb, idx, out, counts, acc);

    // encodings: zero the whole region (clobbers f-scratch, which is now dead), then scatter 1.0s
    hipMemsetAsync(out + O_E, 0, (size_t)NTOK * KCB * 4, stream);
    k_scatter<<<NTOK / 256,                   256, 0, stream>>>(idx, out);
    k_final  <<<1,                            1024, 0, stream>>>(counts, acc, out);
}

// Round 2
// 2044.568 us; speedup vs baseline: 14.5346x; 14.5346x over previous
//
#include <hip/hip_runtime.h>
#include <math.h>

// Problem constants
#define NTOK 131072   // 64 * 2048 tokens
#define DDIM 256      // embedding dim
#define KCB  1024     // codebook size

// Output layout (fp32, concatenated in reference return order)
static constexpr size_t O_Q = 1;                          // quantized_st
static constexpr size_t O_P = 1 + (size_t)NTOK * DDIM;    // perplexity scalar
static constexpr size_t O_E = O_P + 1;                    // encodings [NTOK, KCB]
// f-scratch lives inside the (not yet written) encodings region; +2 floats for 16B alignment
static constexpr size_t SCRATCH_F_OFF = O_E + 2;

// ws layout (bytes)
static constexpr size_t WS_IDX = 0;                        // NTOK * int
static constexpr size_t WS_EN  = (size_t)NTOK * 4;         // KCB * float (||e||^2)
static constexpr size_t WS_CNT = WS_EN + (size_t)KCB * 4;  // KCB * uint (histogram)
static constexpr size_t WS_ACC = WS_CNT + (size_t)KCB * 4; // double (loss accumulator)

#define TS 128     // block tile (tokens and codes)
#define KC 32      // reduction chunk staged in LDS
#define LDSROW 36  // padded row stride: banks offset 4*row mod 32 -> conflict-free reads

// ---------------- K1: codebook squared norms ----------------
__global__ __launch_bounds__(64) void k_enorm(const float* __restrict__ emb,
                                              float* __restrict__ enorm) {
    int k = blockIdx.x;
    float4 v = reinterpret_cast<const float4*>(emb)[(size_t)k * 64 + threadIdx.x];
    float s = v.x * v.x + v.y * v.y + v.z * v.z + v.w * v.w;
    for (int off = 32; off >= 1; off >>= 1) s += __shfl_down(s, off, 64);
    if (threadIdx.x == 0) enorm[k] = s;
}

// Shared inner-product micro-kernel body (register-promotable: acc/bv indexed
// only by fully-unrolled constant-trip loops; is-loop kept rolled on purpose —
// R1 post-mortem: full unroll blew the budget -> arrays demoted to scratch,
// 78 GB of spill traffic).
__device__ __forceinline__ void tile_fma(const float* __restrict__ sA,
                                         const float* __restrict__ sB,
                                         int tx, int ty,
                                         float acc[8][8]) {
#pragma unroll 1
    for (int is = 0; is < 8; ++is) {
        float4 bv[8];
#pragma unroll
        for (int c = 0; c < 8; ++c)
            bv[c] = *reinterpret_cast<const float4*>(&sB[(tx + 16 * c) * LDSROW + is * 4]);
#pragma unroll
        for (int j = 0; j < 8; ++j) {
            float4 a = *reinterpret_cast<const float4*>(&sA[(ty + 16 * j) * LDSROW + is * 4]);
#pragma unroll
            for (int c = 0; c < 8; ++c)
                acc[j][c] += a.x * bv[c].x + a.y * bv[c].y + a.z * bv[c].z + a.w * bv[c].w;
        }
    }
}

__device__ __forceinline__ void stage_tiles(const float4* __restrict__ a4, size_t a_row0,
                                            const float4* __restrict__ b4, size_t b_row0,
                                            int kc, int tid,
                                            float* __restrict__ sA, float* __restrict__ sB) {
#pragma unroll
    for (int l0 = 0; l0 < 4; ++l0) {
        int l = l0 * 256 + tid;          // 1024 float4 per tile
        int row = l >> 3, i4 = l & 7;    // 128 rows x 8 float4
        *reinterpret_cast<float4*>(&sA[row * LDSROW + i4 * 4]) =
            a4[(a_row0 + row) * 64 + kc * 8 + i4];
        *reinterpret_cast<float4*>(&sB[row * LDSROW + i4 * 4]) =
            b4[(b_row0 + row) * 64 + kc * 8 + i4];
    }
}

// ---------------- K2: f = x @ W^T + b  (fp32, 128x128 tile, 8x8 micro) ----------------
__global__ __launch_bounds__(256, 2) void k_gemm1(const float* __restrict__ x,
                                                  const float* __restrict__ w,
                                                  const float* __restrict__ b,
                                                  float* __restrict__ f) {
    __shared__ float sA[TS * LDSROW];
    __shared__ float sB[TS * LDSROW];
    const int tid = threadIdx.x;
    const int tx = tid & 15, ty = tid >> 4;
    const int tb = blockIdx.x * TS;   // token base
    const int db = blockIdx.y * TS;   // output-dim base

    float acc[8][8];
#pragma unroll
    for (int j = 0; j < 8; ++j)
#pragma unroll
        for (int c = 0; c < 8; ++c) acc[j][c] = 0.f;

    const float4* x4 = reinterpret_cast<const float4*>(x);
    const float4* w4 = reinterpret_cast<const float4*>(w);

#pragma unroll 1
    for (int kc = 0; kc < DDIM / KC; ++kc) {
        __syncthreads();
        stage_tiles(x4, tb, w4, db, kc, tid, sA, sB);
        __syncthreads();
        tile_fma(sA, sB, tx, ty, acc);
    }

    float bias[8];
#pragma unroll
    for (int c = 0; c < 8; ++c) bias[c] = b[db + tx + 16 * c];
#pragma unroll
    for (int j = 0; j < 8; ++j) {
        size_t rowo = (size_t)(tb + ty + 16 * j) * DDIM + db;
#pragma unroll
        for (int c = 0; c < 8; ++c)
            f[rowo + tx + 16 * c] = acc[j][c] + bias[c];
    }
}

// ---------------- K3: distances + argmin (fused over all K=1024) ----------------
__global__ __launch_bounds__(256, 2) void k_argmin(const float* __restrict__ f,
                                                   const float* __restrict__ emb,
                                                   const float* __restrict__ enorm,
                                                   int* __restrict__ idx) {
    __shared__ float sA[TS * LDSROW];
    __shared__ float sB[TS * LDSROW];
    const int tid = threadIdx.x;
    const int tx = tid & 15, ty = tid >> 4;
    const int tb = blockIdx.x * TS;
    const float4* f4 = reinterpret_cast<const float4*>(f);
    const float4* e4 = reinterpret_cast<const float4*>(emb);

    float bd[8];
    int   bk[8];
#pragma unroll
    for (int j = 0; j < 8; ++j) { bd[j] = 3.4e38f; bk[j] = 0; }

#pragma unroll 1
    for (int kt = 0; kt < KCB / TS; ++kt) {   // 8 code tiles of 128
        float acc[8][8];
#pragma unroll
        for (int j = 0; j < 8; ++j)
#pragma unroll
            for (int c = 0; c < 8; ++c) acc[j][c] = 0.f;

#pragma unroll 1
        for (int kc = 0; kc < DDIM / KC; ++kc) {
            __syncthreads();
            stage_tiles(f4, tb, e4, (size_t)kt * TS, kc, tid, sA, sB);
            __syncthreads();
            tile_fma(sA, sB, tx, ty, acc);
        }
        // epilogue: d = ||e||^2 - 2*dot  (||f||^2 is token-constant -> irrelevant to argmin)
#pragma unroll
        for (int c = 0; c < 8; ++c) {
            int k = kt * TS + tx + 16 * c;
            float en = enorm[k];
#pragma unroll
            for (int j = 0; j < 8; ++j) {
                float d = en - 2.f * acc[j][c];
                if (d < bd[j] || (d == bd[j] && k < bk[j])) { bd[j] = d; bk[j] = k; }
            }
        }
    }

    // cross-lane lexicographic-min over the 16 tx lanes owning each token row
#pragma unroll
    for (int j = 0; j < 8; ++j) {
#pragma unroll
        for (int m = 1; m < 16; m <<= 1) {
            float od = __shfl_xor(bd[j], m, 16);
            int   ok = __shfl_xor(bk[j], m, 16);
            if (od < bd[j] || (od == bd[j] && ok < bk[j])) { bd[j] = od; bk[j] = ok; }
        }
    }
    if (tx == 0) {
#pragma unroll
        for (int j = 0; j < 8; ++j) idx[tb + ty + 16 * j] = bk[j];
    }
}

// ---------------- K4: quantized gather + commitment-loss partial + histogram ----------------
__global__ __launch_bounds__(256) void k_epilogue(const float* __restrict__ x,
                                                  const float* __restrict__ emb,
                                                  const int* __restrict__ idx,
                                                  float* __restrict__ out,
                                                  unsigned* __restrict__ counts,
                                                  double* __restrict__ lossacc) {
    const int tid = threadIdx.x;
    const int tb = blockIdx.x * 64;  // 64 tokens per block
    const float4* x4 = reinterpret_cast<const float4*>(x);
    const float4* e4 = reinterpret_cast<const float4*>(emb);
    float local = 0.f;
#pragma unroll
    for (int it = 0; it < 16; ++it) {
        int l = it * 256 + tid;
        int tok = l >> 6, q = l & 63;   // token-local float4 index
        int t = tb + tok;
        int id = idx[t];                 // wave-uniform (64 lanes share a token)
        if (q == 0) atomicAdd(&counts[id], 1u);
        float4 xv = x4[(size_t)t * 64 + q];
        float4 ev = e4[(size_t)id * 64 + q];
        size_t o = O_Q + (size_t)t * DDIM + (size_t)q * 4;  // O_Q=1 -> scalar stores (16B-misaligned base)
        out[o] = ev.x; out[o + 1] = ev.y; out[o + 2] = ev.z; out[o + 3] = ev.w;
        float dx = ev.x - xv.x, dy = ev.y - xv.y, dz = ev.z - xv.z, dw = ev.w - xv.w;
        local += dx * dx + dy * dy + dz * dz + dw * dw;
    }
    for (int off = 32; off >= 1; off >>= 1) local += __shfl_down(local, off, 64);
    __shared__ float wsum[4];
    if ((tid & 63) == 0) wsum[tid >> 6] = local;
    __syncthreads();
    if (tid == 0)
        atomicAdd(lossacc, (double)(wsum[0] + wsum[1] + wsum[2] + wsum[3]));
}

// ---------------- K5: scatter one-hot 1.0s (after memset of encodings region) ----------------
__global__ __launch_bounds__(256) void k_scatter(const int* __restrict__ idx,
                                                 float* __restrict__ out) {
    int t = blockIdx.x * 256 + threadIdx.x;
    out[O_E + (size_t)t * KCB + idx[t]] = 1.0f;
}

// ---------------- K6: loss + perplexity finalize ----------------
__global__ __launch_bounds__(1024) void k_final(const unsigned* __restrict__ counts,
                                                const double* __restrict__ lossacc,
                                                float* __restrict__ out) {
    int tid = threadIdx.x;
    double p = (double)counts[tid] / (double)NTOK;
    double term = p * log(p + 1e-10);
    for (int off = 32; off >= 1; off >>= 1) term += __shfl_down(term, off, 64);
    __shared__ double sw[16];
    if ((tid & 63) == 0) sw[tid >> 6] = term;
    __syncthreads();
    if (tid == 0) {
        double s = 0.0;
        for (int i = 0; i < 16; ++i) s += sw[i];
        out[O_P] = (float)exp(-s);
        out[0]   = (float)(0.25 * lossacc[0] / ((double)NTOK * (double)DDIM));
    }
}

extern "C" void kernel_launch(void* const* d_in, const int* in_sizes, int n_in,
                              void* d_out, int out_size, void* d_ws, size_t ws_size,
                              hipStream_t stream) {
    const float* x   = (const float*)d_in[0];  // [64,2048,256]
    const float* w   = (const float*)d_in[1];  // [256,256]
    const float* b   = (const float*)d_in[2];  // [256]
    const float* emb = (const float*)d_in[3];  // [1024,256]
    float* out = (float*)d_out;

    int*      idx    = (int*)((char*)d_ws + WS_IDX);
    float*    enorm  = (float*)((char*)d_ws + WS_EN);
    unsigned* counts = (unsigned*)((char*)d_ws + WS_CNT);
    double*   acc    = (double*)((char*)d_ws + WS_ACC);
    float* scratchF  = out + SCRATCH_F_OFF;    // f staged inside encodings region (written later)

    // zero histogram + loss accumulator (ws is poisoned 0xAA each launch)
    hipMemsetAsync((char*)d_ws + WS_CNT, 0, (size_t)KCB * 4 + 8, stream);

    k_enorm  <<<KCB,                          64,  0, stream>>>(emb, enorm);
    k_gemm1  <<<dim3(NTOK / TS, DDIM / TS),   256, 0, stream>>>(x, w, b, scratchF);
    k_argmin <<<NTOK / TS,                    256, 0, stream>>>(scratchF, emb, enorm, idx);
    k_epilogue<<<NTOK / 64,                   256, 0, stream>>>(x, emb, idx, out, counts, acc);

    // encodings: zero the whole region (clobbers f-scratch, which is now dead), then scatter 1.0s
    hipMemsetAsync(out + O_E, 0, (size_t)NTOK * KCB * 4, stream);
    k_scatter<<<NTOK / 256,                   256, 0, stream>>>(idx, out);
    k_final  <<<1,                            1024, 0, stream>>>(counts, acc, out);
}